// Round 1
// baseline (449.274 us; speedup 1.0000x reference)
//
#include <hip/hip_runtime.h>

typedef unsigned short u16;
typedef __attribute__((ext_vector_type(8))) __bf16 bf16x8;
typedef __attribute__((ext_vector_type(8))) short short8;
typedef __attribute__((ext_vector_type(4))) float f32x4;

__device__ __forceinline__ u16 f2bf(float f) {
  unsigned u = __builtin_bit_cast(unsigned, f);
  u += 0x7fffu + ((u >> 16) & 1u);
  return (u16)(u >> 16);
}

__device__ __forceinline__ void gload_lds16(const void* g, void* l) {
  __builtin_amdgcn_global_load_lds(
      (__attribute__((address_space(1))) void*)g,
      (__attribute__((address_space(3))) void*)l, 16, 0, 0);
}

// ---------------- prep kernels ----------------

__global__ void convert_x_kernel(const float* __restrict__ x, u16* __restrict__ o) {
  int i = blockIdx.x * 256 + threadIdx.x;
  float4 v = ((const float4*)x)[i];
  union { u16 u[4]; uint2 v2; } r;
  r.u[0] = f2bf(v.x); r.u[1] = f2bf(v.y); r.u[2] = f2bf(v.z); r.u[3] = f2bf(v.w);
  ((uint2*)o)[i] = r.v2;
}

// WcatT[n][e], n = sel*1024 + h*64 + hs, value = W{sel}[h][e][hs]
__global__ void build_wcat_kernel(const float* __restrict__ Wq, const float* __restrict__ Wk,
                                  const float* __restrict__ Wv, u16* __restrict__ Wcat) {
  int i = blockIdx.x * 256 + threadIdx.x;   // 3072*1024 total
  int n = i >> 10, e = i & 1023;
  int sel = n >> 10, rem = n & 1023;
  int h = rem >> 6, hs = rem & 63;
  const float* W = (sel == 0) ? Wq : (sel == 1) ? Wk : Wv;
  float v = W[(size_t)(h * 1024 + e) * 64 + hs];
  Wcat[i] = f2bf(v);
}

__global__ void convert_pw_kernel(const float* __restrict__ pw, u16* __restrict__ o) {
  int i = blockIdx.x * 256 + threadIdx.x;
  float4 v = ((const float4*)pw)[i];
  union { u16 u[4]; uint2 v2; } r;
  r.u[0] = f2bf(v.x); r.u[1] = f2bf(v.y); r.u[2] = f2bf(v.z); r.u[3] = f2bf(v.w);
  ((uint2*)o)[i] = r.v2;
}

// ---------------- GEMM: C[M,N] = A[M,K] * BT[N,K]^T (+bias) ----------------
// 128x128 tile, BK=64, 4 waves (2x2), mfma_f32_16x16x32_bf16. m97-style.

template<int OUT_BF16>
__global__ __launch_bounds__(256, 2)
void gemm_bt(const u16* __restrict__ A, const u16* __restrict__ BT,
             void* __restrict__ Cout, const float* __restrict__ bias,
             int M, int N, int K) {
  __shared__ u16 a_lds[128 * 64];
  __shared__ u16 b_lds[128 * 64];
  const int tid = threadIdx.x;
  const int lane = tid & 63;
  const int w = tid >> 6;
  const int wr = w >> 1, wc = w & 1;
  const int mBase = blockIdx.y * 128;
  const int nBase = blockIdx.x * 128;
  const int l15 = lane & 15, l4 = lane >> 4;

  f32x4 acc[4][4] = {};

  for (int k0 = 0; k0 < K; k0 += 64) {
    __syncthreads();
#pragma unroll
    for (int i = 0; i < 4; i++) {
      int idx = i * 2048 + tid * 8;
      int r = idx >> 6, c = idx & 63;
      gload_lds16(A + (size_t)(mBase + r) * K + k0 + c, &a_lds[idx]);
      gload_lds16(BT + (size_t)(nBase + r) * K + k0 + c, &b_lds[idx]);
    }
    asm volatile("s_waitcnt vmcnt(0)" ::: "memory");
    __syncthreads();
#pragma unroll
    for (int kk = 0; kk < 64; kk += 32) {
      bf16x8 af[4], bfr[4];
#pragma unroll
      for (int m = 0; m < 4; m++)
        af[m] = *(const bf16x8*)&a_lds[(wr * 64 + m * 16 + l15) * 64 + kk + l4 * 8];
#pragma unroll
      for (int n = 0; n < 4; n++)
        bfr[n] = *(const bf16x8*)&b_lds[(wc * 64 + n * 16 + l15) * 64 + kk + l4 * 8];
#pragma unroll
      for (int m = 0; m < 4; m++)
#pragma unroll
        for (int n = 0; n < 4; n++)
          acc[m][n] = __builtin_amdgcn_mfma_f32_16x16x32_bf16(af[m], bfr[n], acc[m][n], 0, 0, 0);
    }
  }

#pragma unroll
  for (int m = 0; m < 4; m++) {
    int row = mBase + wr * 64 + m * 16 + l4 * 4;
#pragma unroll
    for (int n = 0; n < 4; n++) {
      int col = nBase + wc * 64 + n * 16 + l15;
#pragma unroll
      for (int j = 0; j < 4; j++) {
        float v = acc[m][n][j];
        if (OUT_BF16) {
          ((u16*)Cout)[(size_t)(row + j) * N + col] = f2bf(v);
        } else {
          ((float*)Cout)[(size_t)(row + j) * N + col] = v + bias[col];
        }
      }
    }
  }
}

// ---------------- flash attention (causal), 64 head-batches ----------------
// QKV [8192][3072] bf16; head-batch hb rows r = hb*2048 + t;
// element (r, d) of Q/K/V at qkv[(r>>4)*3072 + sel*1024 + (r&15)*64 + d].
// Block: 4 waves * 16 q-rows = 64 q-rows. KBLK=64.

__global__ __launch_bounds__(256, 2)
void attn_kernel(const u16* __restrict__ qkv, u16* __restrict__ att) {
  __shared__ u16 k_lds[64 * 64];     // [kpos][d]
  __shared__ u16 vt_lds[64 * 80];    // [d][kpos] padded stride 80
  __shared__ u16 p_lds[4][16 * 80];  // per-wave [q][k] padded stride 80

  const int hb = blockIdx.x >> 5;
  const int qt = blockIdx.x & 31;
  const int q0 = qt * 64;
  const int tid = threadIdx.x;
  const int lane = tid & 63, w = tid >> 6;
  const int l15 = lane & 15, l4 = lane >> 4;
  const int qrow_base = q0 + w * 16;

  // Q fragments in registers (A-frag: row=l15, k=d=kd+l4*8+i)
  bf16x8 aQ[2];
  {
    int t = qrow_base + l15;
    size_t base = (size_t)(hb * 128 + (t >> 4)) * 3072 + (t & 15) * 64;
    aQ[0] = *(const bf16x8*)&qkv[base + 0 + l4 * 8];
    aQ[1] = *(const bf16x8*)&qkv[base + 32 + l4 * 8];
  }

  f32x4 o[4] = {};
  float mrow[4], lrow[4];
#pragma unroll
  for (int j = 0; j < 4; j++) { mrow[j] = -INFINITY; lrow[j] = 0.f; }

  const int nkt = qt + 1;
  for (int kt = 0; kt < nkt; kt++) {
    __syncthreads();
    // stage K tile [64][64] via global_load_lds (2 issues)
#pragma unroll
    for (int i = 0; i < 2; i++) {
      int idx = i * 2048 + tid * 8;
      int kr = idx >> 6, d = idx & 63;
      int t = kt * 64 + kr;
      gload_lds16(&qkv[(size_t)(hb * 128 + (t >> 4)) * 3072 + 1024 + (t & 15) * 64 + d],
                  &k_lds[idx]);
    }
    // stage V transposed: [d][kpos]
#pragma unroll
    for (int i = 0; i < 2; i++) {
      int idx = i * 2048 + tid * 8;
      int kr = idx >> 6, d0 = idx & 63;
      int t = kt * 64 + kr;
      short8 v = *(const short8*)&qkv[(size_t)(hb * 128 + (t >> 4)) * 3072 + 2048 + (t & 15) * 64 + d0];
#pragma unroll
      for (int e = 0; e < 8; e++) vt_lds[(d0 + e) * 80 + kr] = (u16)v[e];
    }
    asm volatile("s_waitcnt vmcnt(0)" ::: "memory");
    __syncthreads();

    // S = Q K^T (per-wave 16x64)
    f32x4 s[4];
#pragma unroll
    for (int n = 0; n < 4; n++) {
      bf16x8 bk0 = *(const bf16x8*)&k_lds[(n * 16 + l15) * 64 + 0 + l4 * 8];
      bf16x8 bk1 = *(const bf16x8*)&k_lds[(n * 16 + l15) * 64 + 32 + l4 * 8];
      f32x4 a = {0.f, 0.f, 0.f, 0.f};
      a = __builtin_amdgcn_mfma_f32_16x16x32_bf16(aQ[0], bk0, a, 0, 0, 0);
      a = __builtin_amdgcn_mfma_f32_16x16x32_bf16(aQ[1], bk1, a, 0, 0, 0);
      s[n] = a;
    }
    // scale + causal mask (D-layout: row=(l>>4)*4+j, col=l&15)
    const int qr0 = qrow_base + l4 * 4;
#pragma unroll
    for (int n = 0; n < 4; n++) {
      int kc = kt * 64 + n * 16 + l15;
#pragma unroll
      for (int j = 0; j < 4; j++) {
        float xv = s[n][j] * 0.125f;
        s[n][j] = (kc > qr0 + j) ? -INFINITY : xv;
      }
    }
    // row max over 4 tiles + 16 lanes
    float pmax[4];
#pragma unroll
    for (int j = 0; j < 4; j++) {
      float mx = fmaxf(fmaxf(s[0][j], s[1][j]), fmaxf(s[2][j], s[3][j]));
      mx = fmaxf(mx, __shfl_xor(mx, 1, 16));
      mx = fmaxf(mx, __shfl_xor(mx, 2, 16));
      mx = fmaxf(mx, __shfl_xor(mx, 4, 16));
      mx = fmaxf(mx, __shfl_xor(mx, 8, 16));
      pmax[j] = mx;
    }
    float alpha[4];
#pragma unroll
    for (int j = 0; j < 4; j++) {
      float mnew = fmaxf(mrow[j], pmax[j]);
      alpha[j] = __expf(mrow[j] - mnew);
      mrow[j] = mnew;
    }
    float psum[4] = {0.f, 0.f, 0.f, 0.f};
    u16 pb[4][4];
#pragma unroll
    for (int n = 0; n < 4; n++)
#pragma unroll
      for (int j = 0; j < 4; j++) {
        float p = __expf(s[n][j] - mrow[j]);
        psum[j] += p;
        pb[n][j] = f2bf(p);
      }
#pragma unroll
    for (int j = 0; j < 4; j++) {
      float su = psum[j];
      su += __shfl_xor(su, 1, 16);
      su += __shfl_xor(su, 2, 16);
      su += __shfl_xor(su, 4, 16);
      su += __shfl_xor(su, 8, 16);
      lrow[j] = alpha[j] * lrow[j] + su;
    }
#pragma unroll
    for (int nd = 0; nd < 4; nd++)
#pragma unroll
      for (int j = 0; j < 4; j++) o[nd][j] *= alpha[j];

    // P -> LDS (per-wave), then PV
#pragma unroll
    for (int n = 0; n < 4; n++)
#pragma unroll
      for (int j = 0; j < 4; j++)
        p_lds[w][(l4 * 4 + j) * 80 + n * 16 + l15] = pb[n][j];
    __syncthreads();
#pragma unroll
    for (int ks = 0; ks < 2; ks++) {
      bf16x8 aP = *(const bf16x8*)&p_lds[w][l15 * 80 + ks * 32 + l4 * 8];
#pragma unroll
      for (int nd = 0; nd < 4; nd++) {
        bf16x8 bV = *(const bf16x8*)&vt_lds[(nd * 16 + l15) * 80 + ks * 32 + l4 * 8];
        o[nd] = __builtin_amdgcn_mfma_f32_16x16x32_bf16(aP, bV, o[nd], 0, 0, 0);
      }
    }
  }

  // epilogue: att[r*64 + d], r = hb*2048 + qr
#pragma unroll
  for (int nd = 0; nd < 4; nd++)
#pragma unroll
    for (int j = 0; j < 4; j++) {
      int qr = qrow_base + l4 * 4 + j;
      size_t r = (size_t)hb * 2048 + qr;
      float v = o[nd][j] / lrow[j];
      att[r * 64 + nd * 16 + l15] = f2bf(v);
    }
}

// ---------------- launch ----------------

extern "C" void kernel_launch(void* const* d_in, const int* in_sizes, int n_in,
                              void* d_out, int out_size, void* d_ws, size_t ws_size,
                              hipStream_t stream) {
  const float* x  = (const float*)d_in[0];
  const float* Wq = (const float*)d_in[1];
  const float* Wk = (const float*)d_in[2];
  const float* Wv = (const float*)d_in[3];
  const float* pw = (const float*)d_in[4];
  const float* pb = (const float*)d_in[5];
  float* out = (float*)d_out;

  char* ws = (char*)d_ws;
  u16* Xb   = (u16*)(ws);                       // 8192*1024*2  = 16 MB
  u16* Wcat = (u16*)(ws + (16u << 20));         // 3072*1024*2  = 6 MB
  u16* PWt  = (u16*)(ws + (22u << 20));         // 1024*1024*2  = 2 MB
  u16* QKV  = (u16*)(ws + (24u << 20));         // 8192*3072*2  = 48 MB
  u16* ATT  = (u16*)(ws + (72u << 20));         // 8192*1024*2  = 16 MB (total 88 MB)

  convert_x_kernel<<<8192, 256, 0, stream>>>(x, Xb);
  build_wcat_kernel<<<12288, 256, 0, stream>>>(Wq, Wk, Wv, Wcat);
  convert_pw_kernel<<<1024, 256, 0, stream>>>(pw, PWt);

  dim3 g1(24, 64);
  gemm_bt<1><<<g1, 256, 0, stream>>>(Xb, Wcat, QKV, nullptr, 8192, 3072, 1024);

  attn_kernel<<<64 * 32, 256, 0, stream>>>(QKV, ATT);

  dim3 g2(8, 64);
  gemm_bt<0><<<g2, 256, 0, stream>>>(ATT, PWt, out, pb, 8192, 1024, 1024);
}

// Round 2
// 241.997 us; speedup vs baseline: 1.8565x; 1.8565x over previous
//
#include <hip/hip_runtime.h>

typedef unsigned short u16;
typedef __attribute__((ext_vector_type(8))) __bf16 bf16x8;
typedef __attribute__((ext_vector_type(8))) short short8;
typedef __attribute__((ext_vector_type(4))) float f32x4;
typedef __attribute__((ext_vector_type(4))) unsigned short ushort4v;

__device__ __forceinline__ u16 f2bf(float f) {
  unsigned u = __builtin_bit_cast(unsigned, f);
  u += 0x7fffu + ((u >> 16) & 1u);
  return (u16)(u >> 16);
}

__device__ __forceinline__ void gload_lds16(const void* g, void* l) {
  __builtin_amdgcn_global_load_lds(
      (__attribute__((address_space(1))) void*)g,
      (__attribute__((address_space(3))) void*)l, 16, 0, 0);
}

// ---------------- prep kernels ----------------

__global__ void convert_x_kernel(const float* __restrict__ x, u16* __restrict__ o) {
  int i = blockIdx.x * 256 + threadIdx.x;
  float4 v = ((const float4*)x)[i];
  union { u16 u[4]; uint2 v2; } r;
  r.u[0] = f2bf(v.x); r.u[1] = f2bf(v.y); r.u[2] = f2bf(v.z); r.u[3] = f2bf(v.w);
  ((uint2*)o)[i] = r.v2;
}

// WcatT[n][e], n = sel*1024 + h*64 + hs, value = W{sel}[h][e][hs]
__global__ void build_wcat_kernel(const float* __restrict__ Wq, const float* __restrict__ Wk,
                                  const float* __restrict__ Wv, u16* __restrict__ Wcat) {
  int i = blockIdx.x * 256 + threadIdx.x;   // 3072*1024 total
  int n = i >> 10, e = i & 1023;
  int sel = n >> 10, rem = n & 1023;
  int h = rem >> 6, hs = rem & 63;
  const float* W = (sel == 0) ? Wq : (sel == 1) ? Wk : Wv;
  float v = W[(size_t)(h * 1024 + e) * 64 + hs];
  Wcat[i] = f2bf(v);
}

__global__ void convert_pw_kernel(const float* __restrict__ pw, u16* __restrict__ o) {
  int i = blockIdx.x * 256 + threadIdx.x;
  float4 v = ((const float4*)pw)[i];
  union { u16 u[4]; uint2 v2; } r;
  r.u[0] = f2bf(v.x); r.u[1] = f2bf(v.y); r.u[2] = f2bf(v.z); r.u[3] = f2bf(v.w);
  ((uint2*)o)[i] = r.v2;
}

// ---------------- GEMM: C[M,N] = A[M,K] * BT[N,K]^T (+bias) ----------------

template<int OUT_BF16>
__global__ __launch_bounds__(256, 2)
void gemm_bt(const u16* __restrict__ A, const u16* __restrict__ BT,
             void* __restrict__ Cout, const float* __restrict__ bias,
             int M, int N, int K) {
  __shared__ u16 a_lds[128 * 64];
  __shared__ u16 b_lds[128 * 64];
  const int tid = threadIdx.x;
  const int lane = tid & 63;
  const int w = tid >> 6;
  const int wr = w >> 1, wc = w & 1;
  const int mBase = blockIdx.y * 128;
  const int nBase = blockIdx.x * 128;
  const int l15 = lane & 15, l4 = lane >> 4;

  f32x4 acc[4][4] = {};

  for (int k0 = 0; k0 < K; k0 += 64) {
    __syncthreads();
#pragma unroll
    for (int i = 0; i < 4; i++) {
      int idx = i * 2048 + tid * 8;
      int r = idx >> 6, c = idx & 63;
      gload_lds16(A + (size_t)(mBase + r) * K + k0 + c, &a_lds[idx]);
      gload_lds16(BT + (size_t)(nBase + r) * K + k0 + c, &b_lds[idx]);
    }
    asm volatile("s_waitcnt vmcnt(0)" ::: "memory");
    __syncthreads();
#pragma unroll
    for (int kk = 0; kk < 64; kk += 32) {
      bf16x8 af[4], bfr[4];
#pragma unroll
      for (int m = 0; m < 4; m++)
        af[m] = *(const bf16x8*)&a_lds[(wr * 64 + m * 16 + l15) * 64 + kk + l4 * 8];
#pragma unroll
      for (int n = 0; n < 4; n++)
        bfr[n] = *(const bf16x8*)&b_lds[(wc * 64 + n * 16 + l15) * 64 + kk + l4 * 8];
#pragma unroll
      for (int m = 0; m < 4; m++)
#pragma unroll
        for (int n = 0; n < 4; n++)
          acc[m][n] = __builtin_amdgcn_mfma_f32_16x16x32_bf16(af[m], bfr[n], acc[m][n], 0, 0, 0);
    }
  }

#pragma unroll
  for (int m = 0; m < 4; m++) {
    int row = mBase + wr * 64 + m * 16 + l4 * 4;
#pragma unroll
    for (int n = 0; n < 4; n++) {
      int col = nBase + wc * 64 + n * 16 + l15;
#pragma unroll
      for (int j = 0; j < 4; j++) {
        float v = acc[m][n][j];
        if (OUT_BF16) {
          ((u16*)Cout)[(size_t)(row + j) * N + col] = f2bf(v);
        } else {
          ((float*)Cout)[(size_t)(row + j) * N + col] = v + bias[col];
        }
      }
    }
  }
}

// ---------------- V transpose: VT[hb][d][t] from QKV V-section ----------------

__global__ __launch_bounds__(256)
void vt_build(const u16* __restrict__ qkv, u16* __restrict__ vt) {
  __shared__ u16 lds[64 * 66];
  const int hb = blockIdx.x >> 5, tc = blockIdx.x & 31;
  const int t0 = tc * 64, tid = threadIdx.x;
#pragma unroll
  for (int i = 0; i < 2; i++) {
    int idx = i * 2048 + tid * 8;
    int tl = idx >> 6, d0 = idx & 63;
    int r = hb * 2048 + t0 + tl;
    const u16* src = &qkv[(size_t)(r >> 4) * 3072 + 2048 + (r & 15) * 64 + d0];
    uint4 v = *(const uint4*)src;
    u16* dst = &lds[tl * 66 + d0];
    *(unsigned*)(dst + 0) = v.x; *(unsigned*)(dst + 2) = v.y;
    *(unsigned*)(dst + 4) = v.z; *(unsigned*)(dst + 6) = v.w;
  }
  __syncthreads();
#pragma unroll
  for (int i = 0; i < 2; i++) {
    int idx = i * 2048 + tid * 8;
    int d = idx >> 6, tl0 = idx & 63;
    union { u16 u[8]; uint4 v; } ou;
#pragma unroll
    for (int e = 0; e < 8; e++) ou.u[e] = lds[(tl0 + e) * 66 + d];
    *(uint4*)&vt[(size_t)hb * 131072 + (size_t)d * 2048 + t0 + tl0] = ou.v;
  }
}

// ---------------- flash attention (causal), swapped-operand form ----------------
// Block: 4 waves x 32 q-rows = 128 q-rows. KBLK=64, double-buffered K/VT tiles.
// S^T = mfma(K, Q)  -> lane owns q = l&15 (per 16-q subtile), k = (l>>4)*4+j
// O^T = mfma(VT, P) -> lane owns q = l&15, d = nd*16 + (l>>4)*4+j

__global__ __launch_bounds__(256, 3)
void attn_kernel(const u16* __restrict__ qkv, const u16* __restrict__ vtg,
                 u16* __restrict__ att) {
  __shared__ u16 k_lds[2][64 * 64];
  __shared__ u16 v_lds[2][64 * 64];
  __shared__ u16 p_lds[4][32 * 72];

  const int wg = (blockIdx.x & 7) * 128 + (blockIdx.x >> 3);  // XCD-bijective swizzle
  const int hb = wg >> 4;
  const int qb = 15 - (wg & 15);                              // heavy blocks first
  const int tid = threadIdx.x;
  const int lane = tid & 63, w = tid >> 6;
  const int l15 = lane & 15, l4 = lane >> 4;
  const int qbase = qb * 128 + w * 32;
  const int nkt = 2 * qb + 2;

  // Q fragments (B-operand: col=q=l15, elems d)
  bf16x8 aQ[2][2];
#pragma unroll
  for (int qs = 0; qs < 2; qs++) {
    int t = qbase + qs * 16 + l15;
    int r = hb * 2048 + t;
    size_t base = (size_t)(r >> 4) * 3072 + (r & 15) * 64;
#pragma unroll
    for (int kc = 0; kc < 2; kc++)
      aQ[qs][kc] = *(const bf16x8*)&qkv[base + kc * 32 + l4 * 8];
  }

  f32x4 o[2][4] = {};
  float mrow[2] = {-INFINITY, -INFINITY};
  float lrow[2] = {0.f, 0.f};

  auto STAGE = [&](int buf, int kt) {
#pragma unroll
    for (int i = 0; i < 2; i++) {
      int U = i * 2048 + tid * 8;
      int row = U >> 6;
      int chunk = ((U >> 3) & 7) ^ (row & 7);     // source-side swizzle (rule 21)
      int rK = hb * 2048 + kt * 64 + row;
      gload_lds16(&qkv[(size_t)(rK >> 4) * 3072 + 1024 + (rK & 15) * 64 + chunk * 8],
                  &k_lds[buf][U]);
    }
#pragma unroll
    for (int i = 0; i < 2; i++) {
      int U = i * 2048 + tid * 8;
      int row = U >> 6;
      int chunk = ((U >> 3) & 7) ^ (row & 7);
      gload_lds16(&vtg[(size_t)hb * 131072 + (size_t)row * 2048 + kt * 64 + chunk * 8],
                  &v_lds[buf][U]);
    }
  };

  STAGE(0, 0);
  asm volatile("s_waitcnt vmcnt(0)" ::: "memory");
  __syncthreads();

  for (int kt = 0; kt < nkt; kt++) {
    if (kt + 1 < nkt) STAGE((kt + 1) & 1, kt + 1);
    const int cur = kt & 1;
    const bool active = (kt * 64 <= qbase + 31);  // wave-uniform
    if (active) {
      // S^T tiles: st[n][qs], k = kt*64 + n*16 + l4*4 + j, q = qbase + qs*16 + l15
      f32x4 st[4][2];
#pragma unroll
      for (int n = 0; n < 4; n++) {
        int row = n * 16 + l15;
        int sw = (row & 7) << 3;
        bf16x8 kf0 = *(const bf16x8*)&k_lds[cur][row * 64 + ((0 + l4 * 8) ^ sw)];
        bf16x8 kf1 = *(const bf16x8*)&k_lds[cur][row * 64 + ((32 + l4 * 8) ^ sw)];
#pragma unroll
        for (int qs = 0; qs < 2; qs++) {
          f32x4 a = {0.f, 0.f, 0.f, 0.f};
          a = __builtin_amdgcn_mfma_f32_16x16x32_bf16(kf0, aQ[qs][0], a, 0, 0, 0);
          a = __builtin_amdgcn_mfma_f32_16x16x32_bf16(kf1, aQ[qs][1], a, 0, 0, 0);
          st[n][qs] = a;
        }
      }
      const bool full = (kt * 64 + 63 <= qbase);  // tile entirely unmasked for wave
#pragma unroll
      for (int qs = 0; qs < 2; qs++) {
        int q = qbase + qs * 16 + l15;
        float tm = -INFINITY;
#pragma unroll
        for (int n = 0; n < 4; n++)
#pragma unroll
          for (int j = 0; j < 4; j++) {
            int k = kt * 64 + n * 16 + l4 * 4 + j;
            float v = st[n][qs][j] * 0.125f;
            if (!full) v = (k > q) ? -INFINITY : v;
            st[n][qs][j] = v;
            tm = fmaxf(tm, v);
          }
        tm = fmaxf(tm, __shfl_xor(tm, 16));
        tm = fmaxf(tm, __shfl_xor(tm, 32));
        float mnew = fmaxf(mrow[qs], tm);
        float alpha = __expf(mrow[qs] - mnew);
        mrow[qs] = mnew;
        float ps = 0.f;
#pragma unroll
        for (int n = 0; n < 4; n++) {
          ushort4v pw;
#pragma unroll
          for (int j = 0; j < 4; j++) {
            float p = __expf(st[n][qs][j] - mnew);
            ps += p;
            pw[j] = f2bf(p);
          }
          // P[q][k] row-major, pitch 72 (2-way conflict = free)
          *(ushort4v*)&p_lds[w][(qs * 16 + l15) * 72 + n * 16 + l4 * 4] = pw;
        }
        ps += __shfl_xor(ps, 16);
        ps += __shfl_xor(ps, 32);
        lrow[qs] = alpha * lrow[qs] + ps;
#pragma unroll
        for (int nd = 0; nd < 4; nd++)
#pragma unroll
          for (int j = 0; j < 4; j++) o[qs][nd][j] *= alpha;
      }
      // PV: O^T += VT_frag(nd,ks) * P_frag(qs,ks)
#pragma unroll
      for (int ks = 0; ks < 2; ks++) {
        bf16x8 pf[2];
#pragma unroll
        for (int qs = 0; qs < 2; qs++)
          pf[qs] = *(const bf16x8*)&p_lds[w][(qs * 16 + l15) * 72 + ks * 32 + l4 * 8];
#pragma unroll
        for (int nd = 0; nd < 4; nd++) {
          int row = nd * 16 + l15;
          int sw = (row & 7) << 3;
          bf16x8 vf = *(const bf16x8*)&v_lds[cur][row * 64 + ((ks * 32 + l4 * 8) ^ sw)];
#pragma unroll
          for (int qs = 0; qs < 2; qs++)
            o[qs][nd] = __builtin_amdgcn_mfma_f32_16x16x32_bf16(vf, pf[qs], o[qs][nd], 0, 0, 0);
        }
      }
    }
    asm volatile("s_waitcnt vmcnt(0)" ::: "memory");
    __syncthreads();
  }

  // epilogue: att[(hb*2048 + q)*64 + d], d = nd*16 + l4*4 + j
#pragma unroll
  for (int qs = 0; qs < 2; qs++) {
    float rl = 1.f / lrow[qs];
    int q = qbase + qs * 16 + l15;
    size_t rbase = ((size_t)hb * 2048 + q) * 64;
#pragma unroll
    for (int nd = 0; nd < 4; nd++) {
      ushort4v ov;
#pragma unroll
      for (int j = 0; j < 4; j++) ov[j] = f2bf(o[qs][nd][j] * rl);
      *(ushort4v*)&att[rbase + nd * 16 + l4 * 4] = ov;
    }
  }
}

// ---------------- launch ----------------

extern "C" void kernel_launch(void* const* d_in, const int* in_sizes, int n_in,
                              void* d_out, int out_size, void* d_ws, size_t ws_size,
                              hipStream_t stream) {
  const float* x  = (const float*)d_in[0];
  const float* Wq = (const float*)d_in[1];
  const float* Wk = (const float*)d_in[2];
  const float* Wv = (const float*)d_in[3];
  const float* pw = (const float*)d_in[4];
  const float* pb = (const float*)d_in[5];
  float* out = (float*)d_out;

  char* ws = (char*)d_ws;
  u16* Xb   = (u16*)(ws);                       // 8192*1024*2  = 16 MB (dead after GEMM1)
  u16* VTg  = (u16*)(ws);                       // 64*64*2048*2 = 16 MB (overlays Xb)
  u16* Wcat = (u16*)(ws + (16u << 20));         // 6 MB
  u16* PWt  = (u16*)(ws + (22u << 20));         // 2 MB
  u16* QKV  = (u16*)(ws + (24u << 20));         // 48 MB
  u16* ATT  = (u16*)(ws + (72u << 20));         // 16 MB (total 88 MB)

  convert_x_kernel<<<8192, 256, 0, stream>>>(x, Xb);
  build_wcat_kernel<<<12288, 256, 0, stream>>>(Wq, Wk, Wv, Wcat);
  convert_pw_kernel<<<1024, 256, 0, stream>>>(pw, PWt);

  dim3 g1(24, 64);
  gemm_bt<1><<<g1, 256, 0, stream>>>(Xb, Wcat, QKV, nullptr, 8192, 3072, 1024);

  vt_build<<<2048, 256, 0, stream>>>(QKV, VTg);

  attn_kernel<<<1024, 256, 0, stream>>>(QKV, VTg, ATT);

  dim3 g2(8, 64);
  gemm_bt<0><<<g2, 256, 0, stream>>>(ATT, PWt, out, pb, 8192, 1024, 1024);
}

// Round 3
// 221.916 us; speedup vs baseline: 2.0245x; 1.0905x over previous
//
#include <hip/hip_runtime.h>

typedef unsigned short u16;
typedef __attribute__((ext_vector_type(8))) __bf16 bf16x8;
typedef __attribute__((ext_vector_type(8))) short short8;
typedef __attribute__((ext_vector_type(4))) float f32x4;
typedef __attribute__((ext_vector_type(4))) unsigned short ushort4v;

__device__ __forceinline__ u16 f2bf(float f) {
  unsigned u = __builtin_bit_cast(unsigned, f);
  u += 0x7fffu + ((u >> 16) & 1u);
  return (u16)(u >> 16);
}

__device__ __forceinline__ float exp2_hw(float x) {
  float r; asm("v_exp_f32 %0, %1" : "=v"(r) : "v"(x)); return r;
}
__device__ __forceinline__ unsigned cvt_pk_bf16(float a, float b) {
  unsigned r; asm("v_cvt_pk_bf16_f32 %0, %1, %2" : "=v"(r) : "v"(a), "v"(b)); return r;
}

__device__ __forceinline__ void gload_lds16(const void* g, void* l) {
  __builtin_amdgcn_global_load_lds(
      (__attribute__((address_space(1))) void*)g,
      (__attribute__((address_space(3))) void*)l, 16, 0, 0);
}

// scale folded into Q at GEMM1 epilogue: 1/sqrt(64) * log2(e)
#define QSCALE 0.1803368801111204f

// ---------------- prep kernels ----------------

__global__ void convert_x_kernel(const float* __restrict__ x, u16* __restrict__ o) {
  int i = blockIdx.x * 256 + threadIdx.x;
  float4 v = ((const float4*)x)[i];
  union { u16 u[4]; uint2 v2; } r;
  r.u[0] = f2bf(v.x); r.u[1] = f2bf(v.y); r.u[2] = f2bf(v.z); r.u[3] = f2bf(v.w);
  ((uint2*)o)[i] = r.v2;
}

// WcatT[n][e], n = sel*1024 + h*64 + hs, value = W{sel}[h][e][hs]
__global__ void build_wcat_kernel(const float* __restrict__ Wq, const float* __restrict__ Wk,
                                  const float* __restrict__ Wv, u16* __restrict__ Wcat) {
  int i = blockIdx.x * 256 + threadIdx.x;   // 3072*1024 total
  int n = i >> 10, e = i & 1023;
  int sel = n >> 10, rem = n & 1023;
  int h = rem >> 6, hs = rem & 63;
  const float* W = (sel == 0) ? Wq : (sel == 1) ? Wk : Wv;
  float v = W[(size_t)(h * 1024 + e) * 64 + hs];
  Wcat[i] = f2bf(v);
}

__global__ void convert_pw_kernel(const float* __restrict__ pw, u16* __restrict__ o) {
  int i = blockIdx.x * 256 + threadIdx.x;
  float4 v = ((const float4*)pw)[i];
  union { u16 u[4]; uint2 v2; } r;
  r.u[0] = f2bf(v.x); r.u[1] = f2bf(v.y); r.u[2] = f2bf(v.z); r.u[3] = f2bf(v.w);
  ((uint2*)o)[i] = r.v2;
}

// ---------------- GEMM: C[M,N] = A[M,K] * BT[N,K]^T (+bias) ----------------
// 1D grid, XCD-chunked bijective swizzle (nwg % 8 == 0), N-panel-major mapping.

template<int OUT_BF16>
__global__ __launch_bounds__(256, 2)
void gemm_bt(const u16* __restrict__ A, const u16* __restrict__ BT,
             void* __restrict__ Cout, const float* __restrict__ bias,
             int M, int N, int K, int gy, int qcols) {
  __shared__ u16 a_lds[128 * 64];
  __shared__ u16 b_lds[128 * 64];
  const int nwg = gridDim.x;
  const int qch = nwg >> 3;
  const int wg = (blockIdx.x & 7) * qch + (blockIdx.x >> 3);
  const int bx = wg / gy, by = wg % gy;
  const int tid = threadIdx.x;
  const int lane = tid & 63;
  const int w = tid >> 6;
  const int wr = w >> 1, wc = w & 1;
  const int mBase = by * 128;
  const int nBase = bx * 128;
  const int l15 = lane & 15, l4 = lane >> 4;

  f32x4 acc[4][4] = {};

  for (int k0 = 0; k0 < K; k0 += 64) {
    __syncthreads();
#pragma unroll
    for (int i = 0; i < 4; i++) {
      int idx = i * 2048 + tid * 8;
      int r = idx >> 6, c = idx & 63;
      gload_lds16(A + (size_t)(mBase + r) * K + k0 + c, &a_lds[idx]);
      gload_lds16(BT + (size_t)(nBase + r) * K + k0 + c, &b_lds[idx]);
    }
    asm volatile("s_waitcnt vmcnt(0)" ::: "memory");
    __syncthreads();
#pragma unroll
    for (int kk = 0; kk < 64; kk += 32) {
      bf16x8 af[4], bfr[4];
#pragma unroll
      for (int m = 0; m < 4; m++)
        af[m] = *(const bf16x8*)&a_lds[(wr * 64 + m * 16 + l15) * 64 + kk + l4 * 8];
#pragma unroll
      for (int n = 0; n < 4; n++)
        bfr[n] = *(const bf16x8*)&b_lds[(wc * 64 + n * 16 + l15) * 64 + kk + l4 * 8];
      __builtin_amdgcn_s_setprio(1);
#pragma unroll
      for (int m = 0; m < 4; m++)
#pragma unroll
        for (int n = 0; n < 4; n++)
          acc[m][n] = __builtin_amdgcn_mfma_f32_16x16x32_bf16(af[m], bfr[n], acc[m][n], 0, 0, 0);
      __builtin_amdgcn_s_setprio(0);
    }
  }

#pragma unroll
  for (int m = 0; m < 4; m++) {
    int row = mBase + wr * 64 + m * 16 + l4 * 4;
#pragma unroll
    for (int n = 0; n < 4; n++) {
      int col = nBase + wc * 64 + n * 16 + l15;
      float scl = (col < qcols) ? QSCALE : 1.f;
#pragma unroll
      for (int j = 0; j < 4; j++) {
        float v = acc[m][n][j];
        if (OUT_BF16) {
          ((u16*)Cout)[(size_t)(row + j) * N + col] = f2bf(v * scl);
        } else {
          ((float*)Cout)[(size_t)(row + j) * N + col] = v + bias[col];
        }
      }
    }
  }
}

// ---------------- V transpose: VT[hb][d][t] from QKV V-section ----------------

__global__ __launch_bounds__(256)
void vt_build(const u16* __restrict__ qkv, u16* __restrict__ vt) {
  __shared__ u16 lds[64 * 66];
  const int hb = blockIdx.x >> 5, tc = blockIdx.x & 31;
  const int t0 = tc * 64, tid = threadIdx.x;
#pragma unroll
  for (int i = 0; i < 2; i++) {
    int idx = i * 2048 + tid * 8;
    int tl = idx >> 6, d0 = idx & 63;
    int r = hb * 2048 + t0 + tl;
    const u16* src = &qkv[(size_t)(r >> 4) * 3072 + 2048 + (r & 15) * 64 + d0];
    uint4 v = *(const uint4*)src;
    u16* dst = &lds[tl * 66 + d0];
    *(unsigned*)(dst + 0) = v.x; *(unsigned*)(dst + 2) = v.y;
    *(unsigned*)(dst + 4) = v.z; *(unsigned*)(dst + 6) = v.w;
  }
  __syncthreads();
#pragma unroll
  for (int i = 0; i < 2; i++) {
    int idx = i * 2048 + tid * 8;
    int d = idx >> 6, tl0 = idx & 63;
    union { u16 u[8]; uint4 v; } ou;
#pragma unroll
    for (int e = 0; e < 8; e++) ou.u[e] = lds[(tl0 + e) * 66 + d];
    *(uint4*)&vt[(size_t)hb * 131072 + (size_t)d * 2048 + t0 + tl0] = ou.v;
  }
}

// ---------------- flash attention (causal), swapped-operand form ----------------
// Q pre-scaled by 1/8*log2e; softmax in exp2 domain.
// S^T = mfma(K, Q)  -> lane owns q = l&15, k = (l>>4)*4+j (per 16-subtile)
// O^T = mfma(VT, P) -> lane owns q = l&15, d = nd*16 + (l>>4)*4+j

__global__ __launch_bounds__(256, 3)
void attn_kernel(const u16* __restrict__ qkv, const u16* __restrict__ vtg,
                 u16* __restrict__ att) {
  __shared__ u16 k_lds[2][64 * 64];
  __shared__ u16 v_lds[2][64 * 64];
  __shared__ u16 p_lds[4][32 * 72];

  const int wg = (blockIdx.x & 7) * 128 + (blockIdx.x >> 3);  // XCD-bijective swizzle
  const int hb = wg >> 4;
  const int qb = 15 - (wg & 15);                              // heavy blocks first
  const int tid = threadIdx.x;
  const int lane = tid & 63, w = tid >> 6;
  const int l15 = lane & 15, l4 = lane >> 4;
  const int qbase = qb * 128 + w * 32;
  const int nkt = 2 * qb + 2;

  // Q fragments (B-operand: col=q=l15, elems d) — pre-scaled
  bf16x8 aQ[2][2];
#pragma unroll
  for (int qs = 0; qs < 2; qs++) {
    int t = qbase + qs * 16 + l15;
    int r = hb * 2048 + t;
    size_t base = (size_t)(r >> 4) * 3072 + (r & 15) * 64;
#pragma unroll
    for (int kc = 0; kc < 2; kc++)
      aQ[qs][kc] = *(const bf16x8*)&qkv[base + kc * 32 + l4 * 8];
  }

  f32x4 o[2][4] = {};
  float mrow[2] = {-INFINITY, -INFINITY};
  float lrow[2] = {0.f, 0.f};

  auto STAGE = [&](int buf, int kt) {
#pragma unroll
    for (int i = 0; i < 2; i++) {
      int U = i * 2048 + tid * 8;
      int row = U >> 6;
      int chunk = ((U >> 3) & 7) ^ (row & 7);     // source-side swizzle (rule 21)
      int rK = hb * 2048 + kt * 64 + row;
      gload_lds16(&qkv[(size_t)(rK >> 4) * 3072 + 1024 + (rK & 15) * 64 + chunk * 8],
                  &k_lds[buf][U]);
    }
#pragma unroll
    for (int i = 0; i < 2; i++) {
      int U = i * 2048 + tid * 8;
      int row = U >> 6;
      int chunk = ((U >> 3) & 7) ^ (row & 7);
      gload_lds16(&vtg[(size_t)hb * 131072 + (size_t)row * 2048 + kt * 64 + chunk * 8],
                  &v_lds[buf][U]);
    }
  };

  STAGE(0, 0);
  asm volatile("s_waitcnt vmcnt(0)" ::: "memory");
  __syncthreads();

  for (int kt = 0; kt < nkt; kt++) {
    if (kt + 1 < nkt) STAGE((kt + 1) & 1, kt + 1);
    const int cur = kt & 1;
    const bool active = (kt * 64 <= qbase + 31);  // wave-uniform
    if (active) {
      // S^T tiles: st[n][qs], k = kt*64 + n*16 + l4*4 + j, q = qbase + qs*16 + l15
      f32x4 st[4][2];
      __builtin_amdgcn_s_setprio(1);
#pragma unroll
      for (int n = 0; n < 4; n++) {
        int row = n * 16 + l15;
        int sw = (row & 7) << 3;
        bf16x8 kf0 = *(const bf16x8*)&k_lds[cur][row * 64 + ((0 + l4 * 8) ^ sw)];
        bf16x8 kf1 = *(const bf16x8*)&k_lds[cur][row * 64 + ((32 + l4 * 8) ^ sw)];
#pragma unroll
        for (int qs = 0; qs < 2; qs++) {
          f32x4 a = {0.f, 0.f, 0.f, 0.f};
          a = __builtin_amdgcn_mfma_f32_16x16x32_bf16(kf0, aQ[qs][0], a, 0, 0, 0);
          a = __builtin_amdgcn_mfma_f32_16x16x32_bf16(kf1, aQ[qs][1], a, 0, 0, 0);
          st[n][qs] = a;
        }
      }
      __builtin_amdgcn_s_setprio(0);
      const bool full = (kt * 64 + 63 <= qbase);  // tile entirely unmasked for wave
#pragma unroll
      for (int qs = 0; qs < 2; qs++) {
        int q = qbase + qs * 16 + l15;
        float tm = -INFINITY;
        if (full) {
#pragma unroll
          for (int n = 0; n < 4; n++)
#pragma unroll
            for (int j = 0; j < 4; j++) tm = fmaxf(tm, st[n][qs][j]);
        } else {
#pragma unroll
          for (int n = 0; n < 4; n++)
#pragma unroll
            for (int j = 0; j < 4; j++) {
              int k = kt * 64 + n * 16 + l4 * 4 + j;
              float v = (k > q) ? -INFINITY : st[n][qs][j];
              st[n][qs][j] = v;
              tm = fmaxf(tm, v);
            }
        }
        tm = fmaxf(tm, __shfl_xor(tm, 16));
        tm = fmaxf(tm, __shfl_xor(tm, 32));
        // defer-max (T13): only rescale when max grew by > 11.5 (log2 domain)
        if (__any(tm > mrow[qs] + 11.5f)) {
          float mnew = fmaxf(mrow[qs], tm);
          float alpha = exp2_hw(mrow[qs] - mnew);
          mrow[qs] = mnew;
          lrow[qs] *= alpha;
#pragma unroll
          for (int nd = 0; nd < 4; nd++)
#pragma unroll
            for (int j = 0; j < 4; j++) o[qs][nd][j] *= alpha;
        }
        float ps = 0.f;
#pragma unroll
        for (int n = 0; n < 4; n++) {
          float p0 = exp2_hw(st[n][qs][0] - mrow[qs]);
          float p1 = exp2_hw(st[n][qs][1] - mrow[qs]);
          float p2 = exp2_hw(st[n][qs][2] - mrow[qs]);
          float p3 = exp2_hw(st[n][qs][3] - mrow[qs]);
          ps += (p0 + p1) + (p2 + p3);
          uint2 pk;
          pk.x = cvt_pk_bf16(p0, p1);
          pk.y = cvt_pk_bf16(p2, p3);
          *(uint2*)&p_lds[w][(qs * 16 + l15) * 72 + n * 16 + l4 * 4] = pk;
        }
        ps += __shfl_xor(ps, 16);
        ps += __shfl_xor(ps, 32);
        lrow[qs] += ps;
      }
      // PV: O^T += VT_frag(nd,ks) * P_frag(qs,ks)
#pragma unroll
      for (int ks = 0; ks < 2; ks++) {
        bf16x8 pf[2];
#pragma unroll
        for (int qs = 0; qs < 2; qs++)
          pf[qs] = *(const bf16x8*)&p_lds[w][(qs * 16 + l15) * 72 + ks * 32 + l4 * 8];
        __builtin_amdgcn_s_setprio(1);
#pragma unroll
        for (int nd = 0; nd < 4; nd++) {
          int row = nd * 16 + l15;
          int sw = (row & 7) << 3;
          bf16x8 vf = *(const bf16x8*)&v_lds[cur][row * 64 + ((ks * 32 + l4 * 8) ^ sw)];
#pragma unroll
          for (int qs = 0; qs < 2; qs++)
            o[qs][nd] = __builtin_amdgcn_mfma_f32_16x16x32_bf16(vf, pf[qs], o[qs][nd], 0, 0, 0);
        }
        __builtin_amdgcn_s_setprio(0);
      }
    }
    asm volatile("s_waitcnt vmcnt(0)" ::: "memory");
    __syncthreads();
  }

  // epilogue: att[(hb*2048 + q)*64 + d], d = nd*16 + l4*4 + j
#pragma unroll
  for (int qs = 0; qs < 2; qs++) {
    float rl = 1.f / lrow[qs];
    int q = qbase + qs * 16 + l15;
    size_t rbase = ((size_t)hb * 2048 + q) * 64;
#pragma unroll
    for (int nd = 0; nd < 4; nd++) {
      ushort4v ov;
#pragma unroll
      for (int j = 0; j < 4; j++) ov[j] = f2bf(o[qs][nd][j] * rl);
      *(ushort4v*)&att[rbase + nd * 16 + l4 * 4] = ov;
    }
  }
}

// ---------------- launch ----------------

extern "C" void kernel_launch(void* const* d_in, const int* in_sizes, int n_in,
                              void* d_out, int out_size, void* d_ws, size_t ws_size,
                              hipStream_t stream) {
  const float* x  = (const float*)d_in[0];
  const float* Wq = (const float*)d_in[1];
  const float* Wk = (const float*)d_in[2];
  const float* Wv = (const float*)d_in[3];
  const float* pw = (const float*)d_in[4];
  const float* pb = (const float*)d_in[5];
  float* out = (float*)d_out;

  char* ws = (char*)d_ws;
  u16* Xb   = (u16*)(ws);                       // 16 MB (dead after GEMM1)
  u16* VTg  = (u16*)(ws);                       // 16 MB (overlays Xb)
  u16* Wcat = (u16*)(ws + (16u << 20));         // 6 MB
  u16* PWt  = (u16*)(ws + (22u << 20));         // 2 MB
  u16* QKV  = (u16*)(ws + (24u << 20));         // 48 MB
  u16* ATT  = (u16*)(ws + (72u << 20));         // 16 MB (total 88 MB)

  convert_x_kernel<<<8192, 256, 0, stream>>>(x, Xb);
  build_wcat_kernel<<<12288, 256, 0, stream>>>(Wq, Wk, Wv, Wcat);
  convert_pw_kernel<<<1024, 256, 0, stream>>>(pw, PWt);

  // GEMM1: M=8192, N=3072, K=1024; Q section (cols<1024) pre-scaled
  gemm_bt<1><<<24 * 64, 256, 0, stream>>>(Xb, Wcat, QKV, nullptr, 8192, 3072, 1024, 64, 1024);

  vt_build<<<2048, 256, 0, stream>>>(QKV, VTg);

  attn_kernel<<<1024, 256, 0, stream>>>(QKV, VTg, ATT);

  // GEMM2: M=8192, N=1024, K=1024, fp32 out + bias
  gemm_bt<0><<<8 * 64, 256, 0, stream>>>(ATT, PWt, out, pb, 8192, 1024, 1024, 64, 0);
}